// Round 6
// baseline (69.279 us; speedup 1.0000x reference)
//
#include <hip/hip_runtime.h>
#include <math.h>

#define MARGIN 0.2f
#define EPSF   1e-16f
#define GRID   256

// B=512 anchors, D=128. Single fused kernel: 256 blocks x 512 threads,
// 2 anchors/block. Per-block partials -> distinct ws slots via device-scope
// atomicExch (no init needed). Ticket atomicAdd on poisoned ws int detects
// the last block (poison 0xAA -> known start value); last block reduces the
// 512 partials and writes out. One dispatch total.
__global__ __launch_bounds__(512) void triplet_fused_kernel(
    const float* __restrict__ embs,   // [512,128] f32
    const int*   __restrict__ ids,    // [512] i32
    float*       __restrict__ out,    // [1] f32
    float*       __restrict__ ws)     // [0..255]=S [256..511]=C [512](int)=ticket
{
    const int bid = blockIdx.x;
    const int tid = threadIdx.x;      // 0..511
    const int g   = tid >> 3;         // 8-lane group id, 0..63
    const int li  = tid & 7;          // lane within group
    const int k0  = li * 16;          // this lane's k-segment
    const int a0  = bid * 2;
    const int a1  = a0 + 1;

    __shared__ float drow0[512];
    __shared__ float drow1[512];
    __shared__ int   sh_ids[512];
    __shared__ int   plist0[64];
    __shared__ int   plist1[64];
    __shared__ int   np0, np1;
    __shared__ float partS[8], partC[8];
    __shared__ int   is_last;

    if (tid == 0) { np0 = 0; np1 = 0; }
    sh_ids[tid] = ids[tid];

    // ---- anchor segments -> registers ----
    float ea0[16], ea1[16];
    {
        const float4* p0 = (const float4*)(embs + a0 * 128 + k0);
        const float4* p1 = (const float4*)(embs + a1 * 128 + k0);
        #pragma unroll
        for (int q = 0; q < 4; ++q) {
            float4 v0 = p0[q];
            ea0[4*q+0] = v0.x; ea0[4*q+1] = v0.y; ea0[4*q+2] = v0.z; ea0[4*q+3] = v0.w;
            float4 v1 = p1[q];
            ea1[4*q+0] = v1.x; ea1[4*q+1] = v1.y; ea1[4*q+2] = v1.z; ea1[4*q+3] = v1.w;
        }
    }
    // anchor norms (reduced across the 8-lane group)
    float na0 = 0.f, na1 = 0.f;
    #pragma unroll
    for (int k = 0; k < 16; ++k) {
        na0 = fmaf(ea0[k], ea0[k], na0);
        na1 = fmaf(ea1[k], ea1[k], na1);
    }
    na0 += __shfl_xor(na0, 1); na0 += __shfl_xor(na0, 2); na0 += __shfl_xor(na0, 4);
    na1 += __shfl_xor(na1, 1); na1 += __shfl_xor(na1, 2); na1 += __shfl_xor(na1, 4);

    __syncthreads();   // sh_ids + np ready

    const int id_a0 = sh_ids[a0];
    const int id_a1 = sh_ids[a1];

    // ---- positive lists (LDS atomic compaction; ~8 entries each) ----
    {
        const int j = tid;
        const int idj = sh_ids[j];
        if (idj == id_a0 && j != a0) { int s = atomicAdd(&np0, 1); plist0[s] = j; }
        if (idj == id_a1 && j != a1) { int s = atomicAdd(&np1, 1); plist1[s] = j; }
    }

    // ---- distance rows via Gram form: d^2 = |a|^2 + |j|^2 - 2 a.j ----
    #pragma unroll
    for (int it = 0; it < 8; ++it) {
        const int col = it * 64 + g;
        const float4* src = (const float4*)(embs + col * 128 + k0);
        float nj = 0.f, dot0 = 0.f, dot1 = 0.f;
        #pragma unroll
        for (int q = 0; q < 4; ++q) {
            float4 v = src[q];
            nj   = fmaf(v.x, v.x, nj);
            nj   = fmaf(v.y, v.y, nj);
            nj   = fmaf(v.z, v.z, nj);
            nj   = fmaf(v.w, v.w, nj);
            dot0 = fmaf(v.x, ea0[4*q+0], dot0);
            dot0 = fmaf(v.y, ea0[4*q+1], dot0);
            dot0 = fmaf(v.z, ea0[4*q+2], dot0);
            dot0 = fmaf(v.w, ea0[4*q+3], dot0);
            dot1 = fmaf(v.x, ea1[4*q+0], dot1);
            dot1 = fmaf(v.y, ea1[4*q+1], dot1);
            dot1 = fmaf(v.z, ea1[4*q+2], dot1);
            dot1 = fmaf(v.w, ea1[4*q+3], dot1);
        }
        nj   += __shfl_xor(nj,   1); nj   += __shfl_xor(nj,   2); nj   += __shfl_xor(nj,   4);
        dot0 += __shfl_xor(dot0, 1); dot0 += __shfl_xor(dot0, 2); dot0 += __shfl_xor(dot0, 4);
        dot1 += __shfl_xor(dot1, 1); dot1 += __shfl_xor(dot1, 2); dot1 += __shfl_xor(dot1, 4);
        if (li == 0) {
            float t0 = na0 + nj - 2.f * dot0;
            float t1 = na1 + nj - 2.f * dot1;
            drow0[col] = (t0 > 0.f) ? sqrtf(t0) : 0.f;
            drow1[col] = (t1 > 0.f) ? sqrtf(t1) : 0.f;
        }
    }
    __syncthreads();

    // ---- triplet accumulation: thread owns negative n = tid ----
    const int   n    = tid;
    const int   idn  = sh_ids[n];
    const float dn0  = drow0[n];
    const float dn1  = drow1[n];
    const int   N0   = np0;
    const int   N1   = np1;

    float s = 0.f, c = 0.f;
    if (idn != id_a0) {
        for (int p = 0; p < N0; ++p) {
            float t = drow0[plist0[p]] + MARGIN - dn0;
            if (t > 0.f)  s += t;
            if (t > EPSF) c += 1.f;
        }
    }
    if (idn != id_a1) {
        for (int p = 0; p < N1; ++p) {
            float t = drow1[plist1[p]] + MARGIN - dn1;
            if (t > 0.f)  s += t;
            if (t > EPSF) c += 1.f;
        }
    }

    // ---- block reduce: 64-lane shfl, then 8 wave partials ----
    #pragma unroll
    for (int off = 1; off < 64; off <<= 1) {
        s += __shfl_xor(s, off);
        c += __shfl_xor(c, off);
    }
    const int wave = tid >> 6;
    if ((tid & 63) == 0) { partS[wave] = s; partC[wave] = c; }
    __syncthreads();

    // ---- publish partials + ticket; last block finishes ----
    if (tid == 0) {
        float S = 0.f, C = 0.f;
        #pragma unroll
        for (int w = 0; w < 8; ++w) { S += partS[w]; C += partC[w]; }
        atomicExch(&ws[bid], S);          // device-scope RMW: coherent publish
        atomicExch(&ws[GRID + bid], C);
        __threadfence();                  // order publish before ticket
        int old = atomicAdd((int*)(ws + 2 * GRID), 1);
        // ws poisoned 0xAA -> ticket starts at (int)0xAAAAAAAA; accept
        // zero-init too for the initial correctness call.
        is_last = (old == (int)0xAAAAAAAAu + (GRID - 1)) || (old == GRID - 1);
    }
    __syncthreads();

    if (is_last) {
        float fs = 0.f, fc = 0.f;
        if (tid < GRID) {
            fs = atomicAdd(&ws[tid], 0.f);         // coherent read of partials
            fc = atomicAdd(&ws[GRID + tid], 0.f);
        }
        #pragma unroll
        for (int off = 1; off < 64; off <<= 1) {
            fs += __shfl_xor(fs, off);
            fc += __shfl_xor(fc, off);
        }
        if ((tid & 63) == 0) { partS[wave] = fs; partC[wave] = fc; }
        __syncthreads();
        if (tid == 0) {
            float S = 0.f, C = 0.f;
            #pragma unroll
            for (int w = 0; w < 8; ++w) { S += partS[w]; C += partC[w]; }
            out[0] = S / (C + EPSF);
        }
    }
}

extern "C" void kernel_launch(void* const* d_in, const int* in_sizes, int n_in,
                              void* d_out, int out_size, void* d_ws, size_t ws_size,
                              hipStream_t stream) {
    const float* embs = (const float*)d_in[0];
    const int*   ids  = (const int*)d_in[1];
    float*       out  = (float*)d_out;
    float*       ws   = (float*)d_ws;

    triplet_fused_kernel<<<GRID, 512, 0, stream>>>(embs, ids, out, ws);
}

// Round 8
// 64.653 us; speedup vs baseline: 1.0716x; 1.0716x over previous
//
#include <hip/hip_runtime.h>
#include <math.h>

#define MARGIN 0.2f
#define EPSF   1e-16f

// B=512 anchors, D=128. Kernel 1: 256 blocks x 512 threads, 2 anchors/block.
// Writes per-block partial (sum, count) to ws[bid], ws[256+bid] with plain
// stores -- no init of ws required, no global atomics.
// (Round-4 configuration: best measured at 65.3 us. The single-dispatch
// fused variant regressed to 69.3 us -- its device-scope threadfence +
// atomic publish/readback tail costs more than the second tiny dispatch.)
__global__ __launch_bounds__(512) void triplet_partial_kernel(
    const float* __restrict__ embs,   // [512,128] f32
    const int*   __restrict__ ids,    // [512] i32
    float*       __restrict__ ws)     // [512] f32 partials
{
    const int bid = blockIdx.x;
    const int tid = threadIdx.x;      // 0..511
    const int g   = tid >> 3;         // 8-lane group id, 0..63
    const int li  = tid & 7;          // lane within group
    const int k0  = li * 16;          // this lane's k-segment
    const int a0  = bid * 2;
    const int a1  = a0 + 1;

    __shared__ float drow0[512];
    __shared__ float drow1[512];
    __shared__ int   sh_ids[512];
    __shared__ int   plist0[64];
    __shared__ int   plist1[64];
    __shared__ int   np0, np1;
    __shared__ float partS[8], partC[8];

    if (tid == 0) { np0 = 0; np1 = 0; }
    sh_ids[tid] = ids[tid];

    // ---- anchor segments -> registers (broadcast loads, L1-served) ----
    float ea0[16], ea1[16];
    {
        const float4* p0 = (const float4*)(embs + a0 * 128 + k0);
        const float4* p1 = (const float4*)(embs + a1 * 128 + k0);
        #pragma unroll
        for (int q = 0; q < 4; ++q) {
            float4 v0 = p0[q];
            ea0[4*q+0] = v0.x; ea0[4*q+1] = v0.y; ea0[4*q+2] = v0.z; ea0[4*q+3] = v0.w;
            float4 v1 = p1[q];
            ea1[4*q+0] = v1.x; ea1[4*q+1] = v1.y; ea1[4*q+2] = v1.z; ea1[4*q+3] = v1.w;
        }
    }
    // anchor norms (reduced across the 8-lane group)
    float na0 = 0.f, na1 = 0.f;
    #pragma unroll
    for (int k = 0; k < 16; ++k) {
        na0 = fmaf(ea0[k], ea0[k], na0);
        na1 = fmaf(ea1[k], ea1[k], na1);
    }
    na0 += __shfl_xor(na0, 1); na0 += __shfl_xor(na0, 2); na0 += __shfl_xor(na0, 4);
    na1 += __shfl_xor(na1, 1); na1 += __shfl_xor(na1, 2); na1 += __shfl_xor(na1, 4);

    __syncthreads();   // sh_ids + np ready

    const int id_a0 = sh_ids[a0];
    const int id_a1 = sh_ids[a1];

    // ---- positive lists (LDS atomic compaction; ~8 entries each) ----
    {
        const int j = tid;
        const int idj = sh_ids[j];
        if (idj == id_a0 && j != a0) { int s = atomicAdd(&np0, 1); plist0[s] = j; }
        if (idj == id_a1 && j != a1) { int s = atomicAdd(&np1, 1); plist1[s] = j; }
    }

    // ---- distance rows via Gram form: d^2 = |a|^2 + |j|^2 - 2 a.j ----
    // 64 groups x 8 cols each
    #pragma unroll
    for (int it = 0; it < 8; ++it) {
        const int col = it * 64 + g;
        const float4* src = (const float4*)(embs + col * 128 + k0);
        float nj = 0.f, dot0 = 0.f, dot1 = 0.f;
        #pragma unroll
        for (int q = 0; q < 4; ++q) {
            float4 v = src[q];
            nj   = fmaf(v.x, v.x, nj);
            nj   = fmaf(v.y, v.y, nj);
            nj   = fmaf(v.z, v.z, nj);
            nj   = fmaf(v.w, v.w, nj);
            dot0 = fmaf(v.x, ea0[4*q+0], dot0);
            dot0 = fmaf(v.y, ea0[4*q+1], dot0);
            dot0 = fmaf(v.z, ea0[4*q+2], dot0);
            dot0 = fmaf(v.w, ea0[4*q+3], dot0);
            dot1 = fmaf(v.x, ea1[4*q+0], dot1);
            dot1 = fmaf(v.y, ea1[4*q+1], dot1);
            dot1 = fmaf(v.z, ea1[4*q+2], dot1);
            dot1 = fmaf(v.w, ea1[4*q+3], dot1);
        }
        nj   += __shfl_xor(nj,   1); nj   += __shfl_xor(nj,   2); nj   += __shfl_xor(nj,   4);
        dot0 += __shfl_xor(dot0, 1); dot0 += __shfl_xor(dot0, 2); dot0 += __shfl_xor(dot0, 4);
        dot1 += __shfl_xor(dot1, 1); dot1 += __shfl_xor(dot1, 2); dot1 += __shfl_xor(dot1, 4);
        if (li == 0) {
            float t0 = na0 + nj - 2.f * dot0;
            float t1 = na1 + nj - 2.f * dot1;
            drow0[col] = (t0 > 0.f) ? sqrtf(t0) : 0.f;
            drow1[col] = (t1 > 0.f) ? sqrtf(t1) : 0.f;
        }
    }
    __syncthreads();

    // ---- triplet accumulation: thread owns negative n = tid ----
    const int   n    = tid;
    const int   idn  = sh_ids[n];
    const float dn0  = drow0[n];
    const float dn1  = drow1[n];
    const int   N0   = np0;
    const int   N1   = np1;

    float s = 0.f, c = 0.f;
    if (idn != id_a0) {
        for (int p = 0; p < N0; ++p) {
            float t = drow0[plist0[p]] + MARGIN - dn0;
            if (t > 0.f)  s += t;
            if (t > EPSF) c += 1.f;
        }
    }
    if (idn != id_a1) {
        for (int p = 0; p < N1; ++p) {
            float t = drow1[plist1[p]] + MARGIN - dn1;
            if (t > 0.f)  s += t;
            if (t > EPSF) c += 1.f;
        }
    }

    // ---- block reduce: 64-lane shfl, then 8 wave partials ----
    #pragma unroll
    for (int off = 1; off < 64; off <<= 1) {
        s += __shfl_xor(s, off);
        c += __shfl_xor(c, off);
    }
    const int wave = tid >> 6;
    if ((tid & 63) == 0) { partS[wave] = s; partC[wave] = c; }
    __syncthreads();

    if (tid == 0) {
        float S = 0.f, C = 0.f;
        #pragma unroll
        for (int w = 0; w < 8; ++w) { S += partS[w]; C += partC[w]; }
        ws[bid]       = S;   // plain stores, distinct slots: no init, no atomics
        ws[256 + bid] = C;
    }
}

// Kernel 2: single block reduces the 256 (S, C) partials.
__global__ __launch_bounds__(256) void triplet_final_kernel(
    const float* __restrict__ ws, float* __restrict__ out)
{
    const int tid = threadIdx.x;
    __shared__ float partS[4], partC[4];

    float s = ws[tid];         // S partial of block tid
    float c = ws[256 + tid];   // C partial of block tid

    #pragma unroll
    for (int off = 1; off < 64; off <<= 1) {
        s += __shfl_xor(s, off);
        c += __shfl_xor(c, off);
    }
    const int wave = tid >> 6;
    if ((tid & 63) == 0) { partS[wave] = s; partC[wave] = c; }
    __syncthreads();

    if (tid == 0) {
        float S = partS[0] + partS[1] + partS[2] + partS[3];
        float C = partC[0] + partC[1] + partC[2] + partC[3];
        out[0] = S / (C + EPSF);
    }
}

extern "C" void kernel_launch(void* const* d_in, const int* in_sizes, int n_in,
                              void* d_out, int out_size, void* d_ws, size_t ws_size,
                              hipStream_t stream) {
    const float* embs = (const float*)d_in[0];
    const int*   ids  = (const int*)d_in[1];
    float*       out  = (float*)d_out;
    float*       ws   = (float*)d_ws;

    triplet_partial_kernel<<<256, 512, 0, stream>>>(embs, ids, ws);
    triplet_final_kernel<<<1, 256, 0, stream>>>(ws, out);
}